// Round 1
// baseline (554.420 us; speedup 1.0000x reference)
//
#include <hip/hip_runtime.h>
#include <math.h>

// ---------------- utility -------------------------------------------------

__global__ __launch_bounds__(256) void k_reduce_sum(const float* __restrict__ v, int n,
                                                    float* __restrict__ out) {
    __shared__ float sdata[4];
    float s = 0.f;
    for (int i = blockIdx.x * 256 + threadIdx.x; i < n; i += gridDim.x * 256) s += v[i];
    for (int o = 1; o < 64; o <<= 1) s += __shfl_xor(s, o, 64);
    if ((threadIdx.x & 63) == 0) sdata[threadIdx.x >> 6] = s;
    __syncthreads();
    if (threadIdx.x == 0) {
        atomicAdd(out, sdata[0] + sdata[1] + sdata[2] + sdata[3]);
    }
}

// ---------------- CSR build (by destination) ------------------------------

__global__ __launch_bounds__(256) void k_count(const int* __restrict__ ei, int E,
                                               int* __restrict__ cnt) {
    int e = blockIdx.x * 256 + threadIdx.x;
    if (e >= E) return;
    atomicAdd(&cnt[ei[E + e]], 1);
}

__global__ __launch_bounds__(256) void k_scan1(const int* __restrict__ cnt, int N,
                                               int* __restrict__ incl, int* __restrict__ aux) {
    __shared__ int tmp[256];
    int tx = threadIdx.x;
    int i = blockIdx.x * 256 + tx;
    int v = (i < N) ? cnt[i] : 0;
    tmp[tx] = v;
    __syncthreads();
    for (int o = 1; o < 256; o <<= 1) {
        int t = (tx >= o) ? tmp[tx - o] : 0;
        __syncthreads();
        tmp[tx] += t;
        __syncthreads();
    }
    if (i < N) incl[i] = tmp[tx];
    if (tx == 255) aux[blockIdx.x] = tmp[255];
}

__global__ __launch_bounds__(256) void k_scan2(int* __restrict__ aux, int NB) {
    __shared__ int tmp[256];
    int tx = threadIdx.x;
    int v = (tx < NB) ? aux[tx] : 0;
    tmp[tx] = v;
    __syncthreads();
    for (int o = 1; o < 256; o <<= 1) {
        int t = (tx >= o) ? tmp[tx - o] : 0;
        __syncthreads();
        tmp[tx] += t;
        __syncthreads();
    }
    if (tx < NB) aux[tx] = tmp[tx];
}

__global__ __launch_bounds__(256) void k_scan3(const int* __restrict__ incl,
                                               const int* __restrict__ cnt,
                                               const int* __restrict__ aux, int N,
                                               int* __restrict__ off, int* __restrict__ cursor) {
    int i = blockIdx.x * 256 + threadIdx.x;
    if (i >= N) return;
    int base = (blockIdx.x > 0) ? aux[blockIdx.x - 1] : 0;
    int o = incl[i] - cnt[i] + base;
    off[i] = o;
    cursor[i] = o;
}

__global__ __launch_bounds__(256) void k_fill(const int* __restrict__ ei,
                                              const float* __restrict__ eattr, int E,
                                              int* __restrict__ cursor,
                                              int* __restrict__ srcs, float* __restrict__ eas) {
    int e = blockIdx.x * 256 + threadIdx.x;
    if (e >= E) return;
    int d = ei[E + e];
    int pos = atomicAdd(&cursor[d], 1);
    srcs[pos] = ei[e];
    eas[pos] = eattr[e];
}

// ---------------- dense linear: Y[N,M] = X[N,128] @ W[128,M] + b ----------

__global__ __launch_bounds__(256) void k_linear(const float* __restrict__ X,
                                                const float* __restrict__ W,
                                                const float* __restrict__ bias,
                                                float* __restrict__ Y, int N, int M) {
    __shared__ float As[32][68];  // As[k][row], pad 68 keeps float4 16B-aligned
    __shared__ float Bs[32][68];  // Bs[k][col]
    int tid = threadIdx.x;
    int tx = tid & 15, ty = tid >> 4;
    int row0 = blockIdx.x * 64;
    int c0 = blockIdx.y * 64;
    float acc[4][4] = {};

    for (int k0 = 0; k0 < 128; k0 += 32) {
        // stage X tile (64 rows x 32 k), transposed
        {
            int kk = tid & 7;       // k-group of 4
            int rbase = tid >> 3;   // 0..31
            for (int i = 0; i < 2; ++i) {
                int r = rbase + i * 32;
                int row = row0 + r;
                float4 v = make_float4(0.f, 0.f, 0.f, 0.f);
                if (row < N) v = *(const float4*)(X + (size_t)row * 128 + k0 + kk * 4);
                As[kk * 4 + 0][r] = v.x;
                As[kk * 4 + 1][r] = v.y;
                As[kk * 4 + 2][r] = v.z;
                As[kk * 4 + 3][r] = v.w;
            }
        }
        // stage W tile (32 k x 64 cols)
        {
            int c = tid & 63;
            int kb = tid >> 6;  // 0..3
            for (int i = 0; i < 8; ++i) {
                int k = kb + i * 4;
                Bs[k][c] = W[(size_t)(k0 + k) * M + c0 + c];
            }
        }
        __syncthreads();
        for (int k = 0; k < 32; ++k) {
            float4 a = *(const float4*)(&As[k][ty * 4]);
            float4 b = *(const float4*)(&Bs[k][tx * 4]);
            float av[4] = {a.x, a.y, a.z, a.w};
            float bv[4] = {b.x, b.y, b.z, b.w};
            for (int i = 0; i < 4; ++i)
                for (int j = 0; j < 4; ++j) acc[i][j] += av[i] * bv[j];
        }
        __syncthreads();
    }
    float4 bvv = *(const float4*)(bias + c0 + tx * 4);
    float bb[4] = {bvv.x, bvv.y, bvv.z, bvv.w};
    for (int i = 0; i < 4; ++i) {
        int row = row0 + ty * 4 + i;
        if (row < N) {
            float4 o;
            o.x = acc[i][0] + bb[0];
            o.y = acc[i][1] + bb[1];
            o.z = acc[i][2] + bb[2];
            o.w = acc[i][3] + bb[3];
            *(float4*)(Y + (size_t)row * M + c0 + tx * 4) = o;
        }
    }
}

// ---------------- GATv2 layer 1 node pass (4 heads x 32, concat) ----------
// one wave per node; lane covers channels (2*lane, 2*lane+1); head = lane/16

__global__ __launch_bounds__(256) void k_node1(const float* __restrict__ xl,
                                               const float* __restrict__ xr,
                                               const int* __restrict__ off,
                                               const int* __restrict__ cnt,
                                               const int* __restrict__ srcs,
                                               const float* __restrict__ eas,
                                               const float* __restrict__ meansum, float invE,
                                               const float* __restrict__ we,
                                               const float* __restrict__ att,
                                               const float* __restrict__ bias,
                                               float* __restrict__ h, int N) {
    int lane = threadIdx.x & 63;
    int node = blockIdx.x * 4 + (threadIdx.x >> 6);
    if (node >= N) return;
    int c0 = lane * 2;
    float2 xrv = *(const float2*)(xr + (size_t)node * 128 + c0);
    float2 wev = *(const float2*)(we + c0);
    float2 attv = *(const float2*)(att + c0);
    float meanattr = meansum[0] * invE;
    int start = off[node], deg = cnt[node];

    float m = -INFINITY, l = 0.f, a0 = 0.f, a1 = 0.f;
    for (int e = 0; e <= deg; ++e) {
        int s;
        float ea;
        if (e < deg) { s = srcs[start + e]; ea = eas[start + e]; }
        else { s = node; ea = meanattr; }  // self-loop
        float2 xlv = *(const float2*)(xl + (size_t)s * 128 + c0);
        float z0 = xlv.x + xrv.x + ea * wev.x;
        float z1 = xlv.y + xrv.y + ea * wev.y;
        z0 = z0 > 0.f ? z0 : 0.2f * z0;
        z1 = z1 > 0.f ? z1 : 0.2f * z1;
        float sc = z0 * attv.x + z1 * attv.y;
        sc += __shfl_xor(sc, 1, 64);
        sc += __shfl_xor(sc, 2, 64);
        sc += __shfl_xor(sc, 4, 64);
        sc += __shfl_xor(sc, 8, 64);  // per-head score, identical in 16-lane group
        float mn = fmaxf(m, sc);
        float scale = expf(m - mn);   // exp(-inf)=0 on first edge
        float p = expf(sc - mn);
        l = l * scale + p;
        a0 = a0 * scale + p * xlv.x;
        a1 = a1 * scale + p * xlv.y;
        m = mn;
    }
    float2 bv = *(const float2*)(bias + c0);
    float o0 = a0 / l + bv.x;
    float o1 = a1 / l + bv.y;
    o0 = o0 > 0.f ? o0 : expm1f(o0);  // elu
    o1 = o1 > 0.f ? o1 : expm1f(o1);
    *(float2*)(h + (size_t)node * 128 + c0) = make_float2(o0, o1);
}

// ---------------- GATv2 layer 2 node pass (2 heads x 32, mean) ------------
// one wave per node; lane = channel (0..63); head = lane/32

__global__ __launch_bounds__(256) void k_node2(const float* __restrict__ xl,
                                               const float* __restrict__ xr,
                                               const int* __restrict__ off,
                                               const int* __restrict__ cnt,
                                               const int* __restrict__ srcs,
                                               const float* __restrict__ eas,
                                               const float* __restrict__ meansum, float invE,
                                               const float* __restrict__ we,
                                               const float* __restrict__ att,
                                               const float* __restrict__ bias,
                                               float* __restrict__ h, int N) {
    int lane = threadIdx.x & 63;
    int node = blockIdx.x * 4 + (threadIdx.x >> 6);
    if (node >= N) return;
    int c = lane;
    float xrv = xr[(size_t)node * 64 + c];
    float wev = we[c];
    float attv = att[c];
    float meanattr = meansum[0] * invE;
    int start = off[node], deg = cnt[node];

    float m = -INFINITY, l = 0.f, a0 = 0.f;
    for (int e = 0; e <= deg; ++e) {
        int s;
        float ea;
        if (e < deg) { s = srcs[start + e]; ea = eas[start + e]; }
        else { s = node; ea = meanattr; }
        float xlv = xl[(size_t)s * 64 + c];
        float z = xlv + xrv + ea * wev;
        z = z > 0.f ? z : 0.2f * z;
        float sc = z * attv;
        sc += __shfl_xor(sc, 1, 64);
        sc += __shfl_xor(sc, 2, 64);
        sc += __shfl_xor(sc, 4, 64);
        sc += __shfl_xor(sc, 8, 64);
        sc += __shfl_xor(sc, 16, 64);  // per-head score across 32-lane group
        float mn = fmaxf(m, sc);
        float scale = expf(m - mn);
        float p = expf(sc - mn);
        l = l * scale + p;
        a0 = a0 * scale + p * xlv;
        m = mn;
    }
    float agg = a0 / l;
    float other = __shfl_xor(agg, 32, 64);
    float o = 0.5f * (agg + other) + bias[c & 31];
    o = o > 0.f ? o : expm1f(o);
    if (lane < 32) h[(size_t)node * 32 + lane] = o;
}

// ---------------- classifier: out[N,8] = h2[N,32] @ wc[32,8] + bc ---------

__global__ __launch_bounds__(256) void k_classify(const float* __restrict__ h2,
                                                  const float* __restrict__ wc,
                                                  const float* __restrict__ bc,
                                                  float* __restrict__ out, int N) {
    int t = blockIdx.x * 256 + threadIdx.x;
    int n = t >> 3, j = t & 7;
    if (n >= N) return;
    float acc = bc[j];
    for (int d = 0; d < 32; ++d) acc += h2[(size_t)n * 32 + d] * wc[d * 8 + j];
    out[(size_t)n * 8 + j] = acc;
}

// ---------------- launch --------------------------------------------------

extern "C" void kernel_launch(void* const* d_in, const int* in_sizes, int n_in,
                              void* d_out, int out_size, void* d_ws, size_t ws_size,
                              hipStream_t stream) {
    const float* x     = (const float*)d_in[0];
    const int*   ei    = (const int*)d_in[1];
    const float* eattr = (const float*)d_in[2];
    const float* w1l = (const float*)d_in[3];
    const float* b1l = (const float*)d_in[4];
    const float* w1r = (const float*)d_in[5];
    const float* b1r = (const float*)d_in[6];
    const float* w1e = (const float*)d_in[7];
    const float* att1 = (const float*)d_in[8];
    const float* bias1 = (const float*)d_in[9];
    const float* w2l = (const float*)d_in[10];
    const float* b2l = (const float*)d_in[11];
    const float* w2r = (const float*)d_in[12];
    const float* b2r = (const float*)d_in[13];
    const float* w2e = (const float*)d_in[14];
    const float* att2 = (const float*)d_in[15];
    const float* bias2 = (const float*)d_in[16];
    const float* wc = (const float*)d_in[17];
    const float* bc = (const float*)d_in[18];
    float* out = (float*)d_out;

    const int N = in_sizes[0] / 128;
    const int E = in_sizes[2];

    // workspace layout
    char* ws = (char*)d_ws;
    size_t o = 0;
    auto alloc = [&](size_t bytes) -> void* {
        void* p = ws + o;
        o += (bytes + 255) & ~(size_t)255;
        return p;
    };
    float* bufA = (float*)alloc((size_t)N * 128 * 4);  // xl1 ; later xl2 (N*64) + h2 (N*32 at +N*64)
    float* bufB = (float*)alloc((size_t)N * 128 * 4);  // xr1 ; later xr2 (N*64)
    float* bufC = (float*)alloc((size_t)N * 128 * 4);  // h1
    int* cnt    = (int*)alloc((size_t)N * 4);
    int* incl   = (int*)alloc((size_t)N * 4);
    int* offb   = (int*)alloc((size_t)N * 4);
    int* cursor = (int*)alloc((size_t)N * 4);
    int* aux    = (int*)alloc(256 * 4);
    int* srcs   = (int*)alloc((size_t)E * 4);
    float* eas  = (float*)alloc((size_t)E * 4);
    float* meansum = (float*)alloc(256);

    float* xl2 = bufA;            // N*64
    float* h2  = bufA + (size_t)N * 64;  // N*32
    float* xr2 = bufB;            // N*64

    const float invE = 1.0f / (float)E;
    const int NB = (N + 255) / 256;

    // zero counters
    hipMemsetAsync(cnt, 0, (size_t)N * 4, stream);
    hipMemsetAsync(meansum, 0, 4, stream);

    // edge_attr mean
    k_reduce_sum<<<256, 256, 0, stream>>>(eattr, E, meansum);

    // CSR build
    k_count<<<(E + 255) / 256, 256, 0, stream>>>(ei, E, cnt);
    k_scan1<<<NB, 256, 0, stream>>>(cnt, N, incl, aux);
    k_scan2<<<1, 256, 0, stream>>>(aux, NB);
    k_scan3<<<NB, 256, 0, stream>>>(incl, cnt, aux, N, offb, cursor);
    k_fill<<<(E + 255) / 256, 256, 0, stream>>>(ei, eattr, E, cursor, srcs, eas);

    // layer 1 transforms
    {
        dim3 grid((N + 63) / 64, 2);
        k_linear<<<grid, 256, 0, stream>>>(x, w1l, b1l, bufA, N, 128);
        k_linear<<<grid, 256, 0, stream>>>(x, w1r, b1r, bufB, N, 128);
    }
    // layer 1 attention + aggregate + elu
    k_node1<<<(N + 3) / 4, 256, 0, stream>>>(bufA, bufB, offb, cnt, srcs, eas, meansum, invE,
                                             w1e, att1, bias1, bufC, N);

    // layer 2 transforms (input h1 = bufC, K=128, M=64)
    {
        dim3 grid((N + 63) / 64, 1);
        k_linear<<<grid, 256, 0, stream>>>(bufC, w2l, b2l, xl2, N, 64);
        k_linear<<<grid, 256, 0, stream>>>(bufC, w2r, b2r, xr2, N, 64);
    }
    // layer 2 attention + aggregate + head-mean + elu
    k_node2<<<(N + 3) / 4, 256, 0, stream>>>(xl2, xr2, offb, cnt, srcs, eas, meansum, invE,
                                             w2e, att2, bias2, h2, N);

    // classifier
    k_classify<<<(N * 8 + 255) / 256, 256, 0, stream>>>(h2, wc, bc, out, N);
}

// Round 2
// 427.960 us; speedup vs baseline: 1.2955x; 1.2955x over previous
//
#include <hip/hip_runtime.h>
#include <math.h>

// ---------------- utility -------------------------------------------------

__global__ __launch_bounds__(256) void k_reduce_sum(const float* __restrict__ v, int n,
                                                    float* __restrict__ out) {
    __shared__ float sdata[4];
    float s = 0.f;
    for (int i = blockIdx.x * 256 + threadIdx.x; i < n; i += gridDim.x * 256) s += v[i];
    for (int o = 1; o < 64; o <<= 1) s += __shfl_xor(s, o, 64);
    if ((threadIdx.x & 63) == 0) sdata[threadIdx.x >> 6] = s;
    __syncthreads();
    if (threadIdx.x == 0) {
        atomicAdd(out, sdata[0] + sdata[1] + sdata[2] + sdata[3]);
    }
}

// ---------------- CSR build (by destination) ------------------------------

__global__ __launch_bounds__(256) void k_count(const int* __restrict__ ei, int E,
                                               int* __restrict__ cnt) {
    int e = blockIdx.x * 256 + threadIdx.x;
    if (e >= E) return;
    atomicAdd(&cnt[ei[E + e]], 1);
}

__global__ __launch_bounds__(256) void k_scan1(const int* __restrict__ cnt, int N,
                                               int* __restrict__ incl, int* __restrict__ aux) {
    __shared__ int tmp[256];
    int tx = threadIdx.x;
    int i = blockIdx.x * 256 + tx;
    int v = (i < N) ? cnt[i] : 0;
    tmp[tx] = v;
    __syncthreads();
    for (int o = 1; o < 256; o <<= 1) {
        int t = (tx >= o) ? tmp[tx - o] : 0;
        __syncthreads();
        tmp[tx] += t;
        __syncthreads();
    }
    if (i < N) incl[i] = tmp[tx];
    if (tx == 255) aux[blockIdx.x] = tmp[255];
}

__global__ __launch_bounds__(256) void k_scan2(int* __restrict__ aux, int NB) {
    __shared__ int tmp[256];
    int tx = threadIdx.x;
    int v = (tx < NB) ? aux[tx] : 0;
    tmp[tx] = v;
    __syncthreads();
    for (int o = 1; o < 256; o <<= 1) {
        int t = (tx >= o) ? tmp[tx - o] : 0;
        __syncthreads();
        tmp[tx] += t;
        __syncthreads();
    }
    if (tx < NB) aux[tx] = tmp[tx];
}

__global__ __launch_bounds__(256) void k_scan3(const int* __restrict__ incl,
                                               const int* __restrict__ cnt,
                                               const int* __restrict__ aux, int N,
                                               int* __restrict__ off, int* __restrict__ cursor) {
    int i = blockIdx.x * 256 + threadIdx.x;
    if (i >= N) return;
    int base = (blockIdx.x > 0) ? aux[blockIdx.x - 1] : 0;
    int o = incl[i] - cnt[i] + base;
    off[i] = o;
    cursor[i] = o;
}

__global__ __launch_bounds__(256) void k_fill(const int* __restrict__ ei,
                                              const float* __restrict__ eattr, int E,
                                              int* __restrict__ cursor,
                                              int* __restrict__ srcs, float* __restrict__ eas) {
    int e = blockIdx.x * 256 + threadIdx.x;
    if (e >= E) return;
    int d = ei[E + e];
    int pos = atomicAdd(&cursor[d], 1);
    srcs[pos] = ei[e];
    eas[pos] = eattr[e];
}

// ---------------- dense linear: Y[N,M] = X[N,128] @ W[128,M] + b ----------

__global__ __launch_bounds__(256) void k_linear(const float* __restrict__ X,
                                                const float* __restrict__ W,
                                                const float* __restrict__ bias,
                                                float* __restrict__ Y, int N, int M) {
    __shared__ float As[32][68];  // As[k][row], pad 68 keeps float4 16B-aligned
    __shared__ float Bs[32][68];  // Bs[k][col]
    int tid = threadIdx.x;
    int tx = tid & 15, ty = tid >> 4;
    int row0 = blockIdx.x * 64;
    int c0 = blockIdx.y * 64;
    float acc[4][4] = {};

    for (int k0 = 0; k0 < 128; k0 += 32) {
        // stage X tile (64 rows x 32 k), transposed
        {
            int kk = tid & 7;       // k-group of 4
            int rbase = tid >> 3;   // 0..31
            for (int i = 0; i < 2; ++i) {
                int r = rbase + i * 32;
                int row = row0 + r;
                float4 v = make_float4(0.f, 0.f, 0.f, 0.f);
                if (row < N) v = *(const float4*)(X + (size_t)row * 128 + k0 + kk * 4);
                As[kk * 4 + 0][r] = v.x;
                As[kk * 4 + 1][r] = v.y;
                As[kk * 4 + 2][r] = v.z;
                As[kk * 4 + 3][r] = v.w;
            }
        }
        // stage W tile (32 k x 64 cols)
        {
            int c = tid & 63;
            int kb = tid >> 6;  // 0..3
            for (int i = 0; i < 8; ++i) {
                int k = kb + i * 4;
                Bs[k][c] = W[(size_t)(k0 + k) * M + c0 + c];
            }
        }
        __syncthreads();
        for (int k = 0; k < 32; ++k) {
            float4 a = *(const float4*)(&As[k][ty * 4]);
            float4 b = *(const float4*)(&Bs[k][tx * 4]);
            float av[4] = {a.x, a.y, a.z, a.w};
            float bv[4] = {b.x, b.y, b.z, b.w};
            for (int i = 0; i < 4; ++i)
                for (int j = 0; j < 4; ++j) acc[i][j] += av[i] * bv[j];
        }
        __syncthreads();
    }
    float4 bvv = *(const float4*)(bias + c0 + tx * 4);
    float bb[4] = {bvv.x, bvv.y, bvv.z, bvv.w};
    for (int i = 0; i < 4; ++i) {
        int row = row0 + ty * 4 + i;
        if (row < N) {
            float4 o;
            o.x = acc[i][0] + bb[0];
            o.y = acc[i][1] + bb[1];
            o.z = acc[i][2] + bb[2];
            o.w = acc[i][3] + bb[3];
            *(float4*)(Y + (size_t)row * M + c0 + tx * 4) = o;
        }
    }
}

// ---------------- GATv2 layer 1 node pass (4 heads x 32, concat) ----------
// one wave per node; lane covers channels (2*lane, 2*lane+1); head = lane/16
// No online max: scores are O(1) (clamped at 60 for exp safety); unroll edge
// loop by 4 so 4 independent gathers are in flight per wave.

__global__ __launch_bounds__(256) void k_node1(const float* __restrict__ xl,
                                               const float* __restrict__ xr,
                                               const int* __restrict__ off,
                                               const int* __restrict__ cnt,
                                               const int* __restrict__ srcs,
                                               const float* __restrict__ eas,
                                               const float* __restrict__ meansum, float invE,
                                               const float* __restrict__ we,
                                               const float* __restrict__ att,
                                               const float* __restrict__ bias,
                                               float* __restrict__ h, int N, int E) {
    int lane = threadIdx.x & 63;
    int node = blockIdx.x * 4 + (threadIdx.x >> 6);
    if (node >= N) return;
    int c0 = lane * 2;
    float2 xrv = *(const float2*)(xr + (size_t)node * 128 + c0);
    float2 wev = *(const float2*)(we + c0);
    float2 attv = *(const float2*)(att + c0);
    float meanattr = meansum[0] * invE;
    int start = off[node], deg = cnt[node];
    int T = deg + 1;  // +1 self-loop (item index deg)
    int Em1 = E - 1;

    float l = 0.f, a0 = 0.f, a1 = 0.f;
    int base = 0;
    for (; base + 4 <= T; base += 4) {
        int s[4];
        float ea[4];
        float2 xv[4];
#pragma unroll
        for (int j = 0; j < 4; ++j) {
            int i = base + j;
            int idx = min(start + i, Em1);
            bool real = i < deg;
            s[j] = real ? srcs[idx] : node;
            ea[j] = real ? eas[idx] : meanattr;
        }
#pragma unroll
        for (int j = 0; j < 4; ++j)
            xv[j] = *(const float2*)(xl + (size_t)s[j] * 128 + c0);
#pragma unroll
        for (int j = 0; j < 4; ++j) {
            float z0 = fmaf(ea[j], wev.x, xv[j].x + xrv.x);
            float z1 = fmaf(ea[j], wev.y, xv[j].y + xrv.y);
            z0 = fmaxf(z0, 0.2f * z0);
            z1 = fmaxf(z1, 0.2f * z1);
            float sc = z0 * attv.x + z1 * attv.y;
            sc += __shfl_xor(sc, 1, 64);
            sc += __shfl_xor(sc, 2, 64);
            sc += __shfl_xor(sc, 4, 64);
            sc += __shfl_xor(sc, 8, 64);  // per-head score (16-lane groups)
            float p = __expf(fminf(sc, 60.f));
            l += p;
            a0 = fmaf(p, xv[j].x, a0);
            a1 = fmaf(p, xv[j].y, a1);
        }
    }
    for (; base < T; ++base) {
        bool real = base < deg;
        int idx = min(start + base, Em1);
        int s = real ? srcs[idx] : node;
        float ea = real ? eas[idx] : meanattr;
        float2 xv = *(const float2*)(xl + (size_t)s * 128 + c0);
        float z0 = fmaf(ea, wev.x, xv.x + xrv.x);
        float z1 = fmaf(ea, wev.y, xv.y + xrv.y);
        z0 = fmaxf(z0, 0.2f * z0);
        z1 = fmaxf(z1, 0.2f * z1);
        float sc = z0 * attv.x + z1 * attv.y;
        sc += __shfl_xor(sc, 1, 64);
        sc += __shfl_xor(sc, 2, 64);
        sc += __shfl_xor(sc, 4, 64);
        sc += __shfl_xor(sc, 8, 64);
        float p = __expf(fminf(sc, 60.f));
        l += p;
        a0 = fmaf(p, xv.x, a0);
        a1 = fmaf(p, xv.y, a1);
    }
    float2 bv = *(const float2*)(bias + c0);
    float inv = 1.0f / l;
    float o0 = fmaf(a0, inv, bv.x);
    float o1 = fmaf(a1, inv, bv.y);
    o0 = o0 > 0.f ? o0 : expm1f(o0);  // elu
    o1 = o1 > 0.f ? o1 : expm1f(o1);
    *(float2*)(h + (size_t)node * 128 + c0) = make_float2(o0, o1);
}

// ---------------- GATv2 layer 2 node pass (2 heads x 32, mean) ------------
// one wave per node; lane = channel (0..63); head = lane/32

__global__ __launch_bounds__(256) void k_node2(const float* __restrict__ xl,
                                               const float* __restrict__ xr,
                                               const int* __restrict__ off,
                                               const int* __restrict__ cnt,
                                               const int* __restrict__ srcs,
                                               const float* __restrict__ eas,
                                               const float* __restrict__ meansum, float invE,
                                               const float* __restrict__ we,
                                               const float* __restrict__ att,
                                               const float* __restrict__ bias,
                                               float* __restrict__ h, int N, int E) {
    int lane = threadIdx.x & 63;
    int node = blockIdx.x * 4 + (threadIdx.x >> 6);
    if (node >= N) return;
    int c = lane;
    float xrv = xr[(size_t)node * 64 + c];
    float wev = we[c];
    float attv = att[c];
    float meanattr = meansum[0] * invE;
    int start = off[node], deg = cnt[node];
    int T = deg + 1;
    int Em1 = E - 1;

    float l = 0.f, a0 = 0.f;
    int base = 0;
    for (; base + 4 <= T; base += 4) {
        int s[4];
        float ea[4];
        float xv[4];
#pragma unroll
        for (int j = 0; j < 4; ++j) {
            int i = base + j;
            int idx = min(start + i, Em1);
            bool real = i < deg;
            s[j] = real ? srcs[idx] : node;
            ea[j] = real ? eas[idx] : meanattr;
        }
#pragma unroll
        for (int j = 0; j < 4; ++j)
            xv[j] = xl[(size_t)s[j] * 64 + c];
#pragma unroll
        for (int j = 0; j < 4; ++j) {
            float z = fmaf(ea[j], wev, xv[j] + xrv);
            z = fmaxf(z, 0.2f * z);
            float sc = z * attv;
            sc += __shfl_xor(sc, 1, 64);
            sc += __shfl_xor(sc, 2, 64);
            sc += __shfl_xor(sc, 4, 64);
            sc += __shfl_xor(sc, 8, 64);
            sc += __shfl_xor(sc, 16, 64);  // per-head score (32-lane groups)
            float p = __expf(fminf(sc, 60.f));
            l += p;
            a0 = fmaf(p, xv[j], a0);
        }
    }
    for (; base < T; ++base) {
        bool real = base < deg;
        int idx = min(start + base, Em1);
        int s = real ? srcs[idx] : node;
        float ea = real ? eas[idx] : meanattr;
        float xv = xl[(size_t)s * 64 + c];
        float z = fmaf(ea, wev, xv + xrv);
        z = fmaxf(z, 0.2f * z);
        float sc = z * attv;
        sc += __shfl_xor(sc, 1, 64);
        sc += __shfl_xor(sc, 2, 64);
        sc += __shfl_xor(sc, 4, 64);
        sc += __shfl_xor(sc, 8, 64);
        sc += __shfl_xor(sc, 16, 64);
        float p = __expf(fminf(sc, 60.f));
        l += p;
        a0 = fmaf(p, xv, a0);
    }
    float agg = a0 / l;
    float other = __shfl_xor(agg, 32, 64);
    float o = 0.5f * (agg + other) + bias[c & 31];
    o = o > 0.f ? o : expm1f(o);
    if (lane < 32) h[(size_t)node * 32 + lane] = o;
}

// ---------------- classifier: out[N,8] = h2[N,32] @ wc[32,8] + bc ---------

__global__ __launch_bounds__(256) void k_classify(const float* __restrict__ h2,
                                                  const float* __restrict__ wc,
                                                  const float* __restrict__ bc,
                                                  float* __restrict__ out, int N) {
    int t = blockIdx.x * 256 + threadIdx.x;
    int n = t >> 3, j = t & 7;
    if (n >= N) return;
    float acc = bc[j];
    for (int d = 0; d < 32; ++d) acc += h2[(size_t)n * 32 + d] * wc[d * 8 + j];
    out[(size_t)n * 8 + j] = acc;
}

// ---------------- launch --------------------------------------------------

extern "C" void kernel_launch(void* const* d_in, const int* in_sizes, int n_in,
                              void* d_out, int out_size, void* d_ws, size_t ws_size,
                              hipStream_t stream) {
    const float* x     = (const float*)d_in[0];
    const int*   ei    = (const int*)d_in[1];
    const float* eattr = (const float*)d_in[2];
    const float* w1l = (const float*)d_in[3];
    const float* b1l = (const float*)d_in[4];
    const float* w1r = (const float*)d_in[5];
    const float* b1r = (const float*)d_in[6];
    const float* w1e = (const float*)d_in[7];
    const float* att1 = (const float*)d_in[8];
    const float* bias1 = (const float*)d_in[9];
    const float* w2l = (const float*)d_in[10];
    const float* b2l = (const float*)d_in[11];
    const float* w2r = (const float*)d_in[12];
    const float* b2r = (const float*)d_in[13];
    const float* w2e = (const float*)d_in[14];
    const float* att2 = (const float*)d_in[15];
    const float* bias2 = (const float*)d_in[16];
    const float* wc = (const float*)d_in[17];
    const float* bc = (const float*)d_in[18];
    float* out = (float*)d_out;

    const int N = in_sizes[0] / 128;
    const int E = in_sizes[2];

    // workspace layout
    char* ws = (char*)d_ws;
    size_t o = 0;
    auto alloc = [&](size_t bytes) -> void* {
        void* p = ws + o;
        o += (bytes + 255) & ~(size_t)255;
        return p;
    };
    float* bufA = (float*)alloc((size_t)N * 128 * 4);  // xl1 ; later xl2 (N*64) + h2 (N*32 at +N*64)
    float* bufB = (float*)alloc((size_t)N * 128 * 4);  // xr1 ; later xr2 (N*64)
    float* bufC = (float*)alloc((size_t)N * 128 * 4);  // h1
    int* cnt    = (int*)alloc((size_t)N * 4);
    int* incl   = (int*)alloc((size_t)N * 4);
    int* offb   = (int*)alloc((size_t)N * 4);
    int* cursor = (int*)alloc((size_t)N * 4);
    int* aux    = (int*)alloc(256 * 4);
    int* srcs   = (int*)alloc((size_t)E * 4);
    float* eas  = (float*)alloc((size_t)E * 4);
    float* meansum = (float*)alloc(256);

    float* xl2 = bufA;            // N*64
    float* h2  = bufA + (size_t)N * 64;  // N*32
    float* xr2 = bufB;            // N*64

    const float invE = 1.0f / (float)E;
    const int NB = (N + 255) / 256;

    // zero counters
    hipMemsetAsync(cnt, 0, (size_t)N * 4, stream);
    hipMemsetAsync(meansum, 0, 4, stream);

    // edge_attr mean
    k_reduce_sum<<<256, 256, 0, stream>>>(eattr, E, meansum);

    // CSR build
    k_count<<<(E + 255) / 256, 256, 0, stream>>>(ei, E, cnt);
    k_scan1<<<NB, 256, 0, stream>>>(cnt, N, incl, aux);
    k_scan2<<<1, 256, 0, stream>>>(aux, NB);
    k_scan3<<<NB, 256, 0, stream>>>(incl, cnt, aux, N, offb, cursor);
    k_fill<<<(E + 255) / 256, 256, 0, stream>>>(ei, eattr, E, cursor, srcs, eas);

    // layer 1 transforms
    {
        dim3 grid((N + 63) / 64, 2);
        k_linear<<<grid, 256, 0, stream>>>(x, w1l, b1l, bufA, N, 128);
        k_linear<<<grid, 256, 0, stream>>>(x, w1r, b1r, bufB, N, 128);
    }
    // layer 1 attention + aggregate + elu
    k_node1<<<(N + 3) / 4, 256, 0, stream>>>(bufA, bufB, offb, cnt, srcs, eas, meansum, invE,
                                             w1e, att1, bias1, bufC, N, E);

    // layer 2 transforms (input h1 = bufC, K=128, M=64)
    {
        dim3 grid((N + 63) / 64, 1);
        k_linear<<<grid, 256, 0, stream>>>(bufC, w2l, b2l, xl2, N, 64);
        k_linear<<<grid, 256, 0, stream>>>(bufC, w2r, b2r, xr2, N, 64);
    }
    // layer 2 attention + aggregate + head-mean + elu
    k_node2<<<(N + 3) / 4, 256, 0, stream>>>(xl2, xr2, offb, cnt, srcs, eas, meansum, invE,
                                             w2e, att2, bias2, h2, N, E);

    // classifier
    k_classify<<<(N * 8 + 255) / 256, 256, 0, stream>>>(h2, wc, bc, out, N);
}

// Round 3
// 419.250 us; speedup vs baseline: 1.3224x; 1.0208x over previous
//
#include <hip/hip_runtime.h>
#include <hip/hip_fp16.h>
#include <math.h>

// ---------------- utility -------------------------------------------------

__global__ __launch_bounds__(256) void k_reduce_sum(const float* __restrict__ v, int n,
                                                    float* __restrict__ out) {
    __shared__ float sdata[4];
    float s = 0.f;
    for (int i = blockIdx.x * 256 + threadIdx.x; i < n; i += gridDim.x * 256) s += v[i];
    for (int o = 1; o < 64; o <<= 1) s += __shfl_xor(s, o, 64);
    if ((threadIdx.x & 63) == 0) sdata[threadIdx.x >> 6] = s;
    __syncthreads();
    if (threadIdx.x == 0) {
        atomicAdd(out, sdata[0] + sdata[1] + sdata[2] + sdata[3]);
    }
}

// ---------------- CSR build (by destination) ------------------------------

__global__ __launch_bounds__(256) void k_count(const int* __restrict__ ei, int E,
                                               int* __restrict__ cnt) {
    int e = blockIdx.x * 256 + threadIdx.x;
    if (e >= E) return;
    atomicAdd(&cnt[ei[E + e]], 1);
}

__global__ __launch_bounds__(256) void k_scan1(const int* __restrict__ cnt, int N,
                                               int* __restrict__ incl, int* __restrict__ aux) {
    __shared__ int tmp[256];
    int tx = threadIdx.x;
    int i = blockIdx.x * 256 + tx;
    int v = (i < N) ? cnt[i] : 0;
    tmp[tx] = v;
    __syncthreads();
    for (int o = 1; o < 256; o <<= 1) {
        int t = (tx >= o) ? tmp[tx - o] : 0;
        __syncthreads();
        tmp[tx] += t;
        __syncthreads();
    }
    if (i < N) incl[i] = tmp[tx];
    if (tx == 255) aux[blockIdx.x] = tmp[255];
}

__global__ __launch_bounds__(256) void k_scan2(int* __restrict__ aux, int NB) {
    __shared__ int tmp[256];
    int tx = threadIdx.x;
    int v = (tx < NB) ? aux[tx] : 0;
    tmp[tx] = v;
    __syncthreads();
    for (int o = 1; o < 256; o <<= 1) {
        int t = (tx >= o) ? tmp[tx - o] : 0;
        __syncthreads();
        tmp[tx] += t;
        __syncthreads();
    }
    if (tx < NB) aux[tx] = tmp[tx];
}

__global__ __launch_bounds__(256) void k_scan3(const int* __restrict__ incl,
                                               const int* __restrict__ cnt,
                                               const int* __restrict__ aux, int N,
                                               int* __restrict__ off, int* __restrict__ cursor) {
    int i = blockIdx.x * 256 + threadIdx.x;
    if (i >= N) return;
    int base = (blockIdx.x > 0) ? aux[blockIdx.x - 1] : 0;
    int o = incl[i] - cnt[i] + base;
    off[i] = o;
    cursor[i] = o;
}

// packs (src, bitcast(edge_attr)) per CSR slot
__global__ __launch_bounds__(256) void k_fill(const int* __restrict__ ei,
                                              const float* __restrict__ eattr, int E,
                                              int* __restrict__ cursor,
                                              int2* __restrict__ edges) {
    int e = blockIdx.x * 256 + threadIdx.x;
    if (e >= E) return;
    int d = ei[E + e];
    int pos = atomicAdd(&cursor[d], 1);
    edges[pos] = make_int2(ei[e], __float_as_int(eattr[e]));
}

// ---------------- dense linear: Y[N,M] = X[N,128] @ W[128,M] + b ----------
// Writes f32 (Y) or fp16 (Yh) depending on which pointer is non-null.

__global__ __launch_bounds__(256) void k_linear(const float* __restrict__ X,
                                                const float* __restrict__ W,
                                                const float* __restrict__ bias,
                                                float* __restrict__ Y,
                                                __half* __restrict__ Yh, int N, int M) {
    __shared__ float As[32][68];  // As[k][row], pad 68 keeps float4 16B-aligned
    __shared__ float Bs[32][68];  // Bs[k][col]
    int tid = threadIdx.x;
    int tx = tid & 15, ty = tid >> 4;
    int row0 = blockIdx.x * 64;
    int c0 = blockIdx.y * 64;
    float acc[4][4] = {};

    for (int k0 = 0; k0 < 128; k0 += 32) {
        // stage X tile (64 rows x 32 k), transposed
        {
            int kk = tid & 7;       // k-group of 4
            int rbase = tid >> 3;   // 0..31
            for (int i = 0; i < 2; ++i) {
                int r = rbase + i * 32;
                int row = row0 + r;
                float4 v = make_float4(0.f, 0.f, 0.f, 0.f);
                if (row < N) v = *(const float4*)(X + (size_t)row * 128 + k0 + kk * 4);
                As[kk * 4 + 0][r] = v.x;
                As[kk * 4 + 1][r] = v.y;
                As[kk * 4 + 2][r] = v.z;
                As[kk * 4 + 3][r] = v.w;
            }
        }
        // stage W tile (32 k x 64 cols)
        {
            int c = tid & 63;
            int kb = tid >> 6;  // 0..3
            for (int i = 0; i < 8; ++i) {
                int k = kb + i * 4;
                Bs[k][c] = W[(size_t)(k0 + k) * M + c0 + c];
            }
        }
        __syncthreads();
        for (int k = 0; k < 32; ++k) {
            float4 a = *(const float4*)(&As[k][ty * 4]);
            float4 b = *(const float4*)(&Bs[k][tx * 4]);
            float av[4] = {a.x, a.y, a.z, a.w};
            float bv[4] = {b.x, b.y, b.z, b.w};
            for (int i = 0; i < 4; ++i)
                for (int j = 0; j < 4; ++j) acc[i][j] += av[i] * bv[j];
        }
        __syncthreads();
    }
    float4 bvv = *(const float4*)(bias + c0 + tx * 4);
    float bb[4] = {bvv.x, bvv.y, bvv.z, bvv.w};
    for (int i = 0; i < 4; ++i) {
        int row = row0 + ty * 4 + i;
        if (row < N) {
            float o0 = acc[i][0] + bb[0];
            float o1 = acc[i][1] + bb[1];
            float o2 = acc[i][2] + bb[2];
            float o3 = acc[i][3] + bb[3];
            if (Y) {
                *(float4*)(Y + (size_t)row * M + c0 + tx * 4) = make_float4(o0, o1, o2, o3);
            } else {
                __half2* p = (__half2*)(Yh + (size_t)row * M + c0 + tx * 4);
                p[0] = __floats2half2_rn(o0, o1);
                p[1] = __floats2half2_rn(o2, o3);
            }
        }
    }
}

// ---------------- GATv2 layer 1 node pass (4 heads x 32, concat) ----------
// one wave per node; lane covers channels (2*lane, 2*lane+1); head = lane/16
// xl gather table is fp16 (halves HBM/L3 traffic). No online max (scores O(1),
// clamped at 60). Predicate-free unroll-8 main loop; predicated tail handles
// remainder + self-loop.

__global__ __launch_bounds__(256) void k_node1(const __half* __restrict__ xlh,
                                               const float* __restrict__ xr,
                                               const int* __restrict__ off,
                                               const int* __restrict__ cnt,
                                               const int2* __restrict__ edges,
                                               const float* __restrict__ meansum, float invE,
                                               const float* __restrict__ we,
                                               const float* __restrict__ att,
                                               const float* __restrict__ bias,
                                               float* __restrict__ h, int N) {
    int lane = threadIdx.x & 63;
    int node = blockIdx.x * 4 + (threadIdx.x >> 6);
    if (node >= N) return;
    int c0 = lane * 2;
    float2 xrv = *(const float2*)(xr + (size_t)node * 128 + c0);
    float2 wev = *(const float2*)(we + c0);
    float2 attv = *(const float2*)(att + c0);
    float meanattr = meansum[0] * invE;
    int start = off[node], deg = cnt[node];

    float l = 0.f, a0 = 0.f, a1 = 0.f;
    int full = deg & ~7;
    int base = 0;
    for (; base < full; base += 8) {
        int2 ed[8];
        float2 xv[8];
#pragma unroll
        for (int j = 0; j < 8; ++j) ed[j] = edges[start + base + j];
#pragma unroll
        for (int j = 0; j < 8; ++j)
            xv[j] = __half22float2(*(const __half2*)(xlh + (size_t)ed[j].x * 128 + c0));
#pragma unroll
        for (int j = 0; j < 8; ++j) {
            float ea = __int_as_float(ed[j].y);
            float z0 = fmaf(ea, wev.x, xv[j].x + xrv.x);
            float z1 = fmaf(ea, wev.y, xv[j].y + xrv.y);
            z0 = fmaxf(z0, 0.2f * z0);
            z1 = fmaxf(z1, 0.2f * z1);
            float sc = z0 * attv.x + z1 * attv.y;
            sc += __shfl_xor(sc, 1, 64);
            sc += __shfl_xor(sc, 2, 64);
            sc += __shfl_xor(sc, 4, 64);
            sc += __shfl_xor(sc, 8, 64);  // per-head score (16-lane groups)
            float p = __expf(fminf(sc, 60.f));
            l += p;
            a0 = fmaf(p, xv[j].x, a0);
            a1 = fmaf(p, xv[j].y, a1);
        }
    }
    for (int i = base; i <= deg; ++i) {   // remainder + self-loop (i==deg)
        bool real = i < deg;
        int2 ed = real ? edges[start + i] : make_int2(node, __float_as_int(meanattr));
        float ea = __int_as_float(ed.y);
        float2 xv = __half22float2(*(const __half2*)(xlh + (size_t)ed.x * 128 + c0));
        float z0 = fmaf(ea, wev.x, xv.x + xrv.x);
        float z1 = fmaf(ea, wev.y, xv.y + xrv.y);
        z0 = fmaxf(z0, 0.2f * z0);
        z1 = fmaxf(z1, 0.2f * z1);
        float sc = z0 * attv.x + z1 * attv.y;
        sc += __shfl_xor(sc, 1, 64);
        sc += __shfl_xor(sc, 2, 64);
        sc += __shfl_xor(sc, 4, 64);
        sc += __shfl_xor(sc, 8, 64);
        float p = __expf(fminf(sc, 60.f));
        l += p;
        a0 = fmaf(p, xv.x, a0);
        a1 = fmaf(p, xv.y, a1);
    }
    float2 bv = *(const float2*)(bias + c0);
    float inv = 1.0f / l;
    float o0 = fmaf(a0, inv, bv.x);
    float o1 = fmaf(a1, inv, bv.y);
    o0 = o0 > 0.f ? o0 : expm1f(o0);  // elu
    o1 = o1 > 0.f ? o1 : expm1f(o1);
    *(float2*)(h + (size_t)node * 128 + c0) = make_float2(o0, o1);
}

// ---------------- GATv2 layer 2 node pass (2 heads x 32, mean) ------------
// one wave per node; lane = channel (0..63); head = lane/32; xl fp16.

__global__ __launch_bounds__(256) void k_node2(const __half* __restrict__ xlh,
                                               const float* __restrict__ xr,
                                               const int* __restrict__ off,
                                               const int* __restrict__ cnt,
                                               const int2* __restrict__ edges,
                                               const float* __restrict__ meansum, float invE,
                                               const float* __restrict__ we,
                                               const float* __restrict__ att,
                                               const float* __restrict__ bias,
                                               float* __restrict__ h, int N) {
    int lane = threadIdx.x & 63;
    int node = blockIdx.x * 4 + (threadIdx.x >> 6);
    if (node >= N) return;
    int c = lane;
    float xrv = xr[(size_t)node * 64 + c];
    float wev = we[c];
    float attv = att[c];
    float meanattr = meansum[0] * invE;
    int start = off[node], deg = cnt[node];

    float l = 0.f, a0 = 0.f;
    int full = deg & ~7;
    int base = 0;
    for (; base < full; base += 8) {
        int2 ed[8];
        float xv[8];
#pragma unroll
        for (int j = 0; j < 8; ++j) ed[j] = edges[start + base + j];
#pragma unroll
        for (int j = 0; j < 8; ++j)
            xv[j] = __half2float(xlh[(size_t)ed[j].x * 64 + c]);
#pragma unroll
        for (int j = 0; j < 8; ++j) {
            float ea = __int_as_float(ed[j].y);
            float z = fmaf(ea, wev, xv[j] + xrv);
            z = fmaxf(z, 0.2f * z);
            float sc = z * attv;
            sc += __shfl_xor(sc, 1, 64);
            sc += __shfl_xor(sc, 2, 64);
            sc += __shfl_xor(sc, 4, 64);
            sc += __shfl_xor(sc, 8, 64);
            sc += __shfl_xor(sc, 16, 64);  // per-head score (32-lane groups)
            float p = __expf(fminf(sc, 60.f));
            l += p;
            a0 = fmaf(p, xv[j], a0);
        }
    }
    for (int i = base; i <= deg; ++i) {
        bool real = i < deg;
        int2 ed = real ? edges[start + i] : make_int2(node, __float_as_int(meanattr));
        float ea = __int_as_float(ed.y);
        float xv = __half2float(xlh[(size_t)ed.x * 64 + c]);
        float z = fmaf(ea, wev, xv + xrv);
        z = fmaxf(z, 0.2f * z);
        float sc = z * attv;
        sc += __shfl_xor(sc, 1, 64);
        sc += __shfl_xor(sc, 2, 64);
        sc += __shfl_xor(sc, 4, 64);
        sc += __shfl_xor(sc, 8, 64);
        sc += __shfl_xor(sc, 16, 64);
        float p = __expf(fminf(sc, 60.f));
        l += p;
        a0 = fmaf(p, xv, a0);
    }
    float agg = a0 / l;
    float other = __shfl_xor(agg, 32, 64);
    float o = 0.5f * (agg + other) + bias[c & 31];
    o = o > 0.f ? o : expm1f(o);
    if (lane < 32) h[(size_t)node * 32 + lane] = o;
}

// ---------------- classifier: out[N,8] = h2[N,32] @ wc[32,8] + bc ---------

__global__ __launch_bounds__(256) void k_classify(const float* __restrict__ h2,
                                                  const float* __restrict__ wc,
                                                  const float* __restrict__ bc,
                                                  float* __restrict__ out, int N) {
    int t = blockIdx.x * 256 + threadIdx.x;
    int n = t >> 3, j = t & 7;
    if (n >= N) return;
    float acc = bc[j];
    for (int d = 0; d < 32; ++d) acc += h2[(size_t)n * 32 + d] * wc[d * 8 + j];
    out[(size_t)n * 8 + j] = acc;
}

// ---------------- launch --------------------------------------------------

extern "C" void kernel_launch(void* const* d_in, const int* in_sizes, int n_in,
                              void* d_out, int out_size, void* d_ws, size_t ws_size,
                              hipStream_t stream) {
    const float* x     = (const float*)d_in[0];
    const int*   ei    = (const int*)d_in[1];
    const float* eattr = (const float*)d_in[2];
    const float* w1l = (const float*)d_in[3];
    const float* b1l = (const float*)d_in[4];
    const float* w1r = (const float*)d_in[5];
    const float* b1r = (const float*)d_in[6];
    const float* w1e = (const float*)d_in[7];
    const float* att1 = (const float*)d_in[8];
    const float* bias1 = (const float*)d_in[9];
    const float* w2l = (const float*)d_in[10];
    const float* b2l = (const float*)d_in[11];
    const float* w2r = (const float*)d_in[12];
    const float* b2r = (const float*)d_in[13];
    const float* w2e = (const float*)d_in[14];
    const float* att2 = (const float*)d_in[15];
    const float* bias2 = (const float*)d_in[16];
    const float* wc = (const float*)d_in[17];
    const float* bc = (const float*)d_in[18];
    float* out = (float*)d_out;

    const int N = in_sizes[0] / 128;
    const int E = in_sizes[2];

    // workspace layout (with liveness-based reuse)
    char* ws = (char*)d_ws;
    size_t o = 0;
    auto alloc = [&](size_t bytes) -> void* {
        void* p = ws + o;
        o += (bytes + 255) & ~(size_t)255;
        return p;
    };
    __half* xl1h = (__half*)alloc((size_t)N * 128 * 2);  // fp16 gather table L1; later h2 (N*32*4)
    float* xr1   = (float*)alloc((size_t)N * 128 * 4);   // f32; later xl2h (N*64*2) + xr2 (N*64*4)
    float* h1    = (float*)alloc((size_t)N * 128 * 4);
    int* cnt    = (int*)alloc((size_t)N * 4);
    int* incl   = (int*)alloc((size_t)N * 4);
    int* offb   = (int*)alloc((size_t)N * 4);
    int* cursor = (int*)alloc((size_t)N * 4);
    int* aux    = (int*)alloc(256 * 4);
    int2* edges = (int2*)alloc((size_t)E * 8);
    float* meansum = (float*)alloc(256);

    __half* xl2h = (__half*)xr1;                     // N*64 halves (xr1 dead by then)
    float*  xr2  = (float*)((char*)xr1 + (size_t)N * 64 * 2 + 256);  // N*64 f32
    xr2 = (float*)(((uintptr_t)xr2 + 255) & ~(uintptr_t)255);
    float*  h2   = (float*)xl1h;                     // N*32 f32 (xl1h dead by then)

    const float invE = 1.0f / (float)E;
    const int NB = (N + 255) / 256;

    // zero counters
    hipMemsetAsync(cnt, 0, (size_t)N * 4, stream);
    hipMemsetAsync(meansum, 0, 4, stream);

    // edge_attr mean
    k_reduce_sum<<<256, 256, 0, stream>>>(eattr, E, meansum);

    // CSR build
    k_count<<<(E + 255) / 256, 256, 0, stream>>>(ei, E, cnt);
    k_scan1<<<NB, 256, 0, stream>>>(cnt, N, incl, aux);
    k_scan2<<<1, 256, 0, stream>>>(aux, NB);
    k_scan3<<<NB, 256, 0, stream>>>(incl, cnt, aux, N, offb, cursor);
    k_fill<<<(E + 255) / 256, 256, 0, stream>>>(ei, eattr, E, cursor, edges);

    // layer 1 transforms: xl -> fp16 table, xr -> f32
    {
        dim3 grid((N + 63) / 64, 2);
        k_linear<<<grid, 256, 0, stream>>>(x, w1l, b1l, nullptr, xl1h, N, 128);
        k_linear<<<grid, 256, 0, stream>>>(x, w1r, b1r, xr1, nullptr, N, 128);
    }
    // layer 1 attention + aggregate + elu
    k_node1<<<(N + 3) / 4, 256, 0, stream>>>(xl1h, xr1, offb, cnt, edges, meansum, invE,
                                             w1e, att1, bias1, h1, N);

    // layer 2 transforms (input h1, K=128, M=64): xl -> fp16 table, xr -> f32
    {
        dim3 grid((N + 63) / 64, 1);
        k_linear<<<grid, 256, 0, stream>>>(h1, w2l, b2l, nullptr, xl2h, N, 64);
        k_linear<<<grid, 256, 0, stream>>>(h1, w2r, b2r, xr2, nullptr, N, 64);
    }
    // layer 2 attention + aggregate + head-mean + elu
    k_node2<<<(N + 3) / 4, 256, 0, stream>>>(xl2h, xr2, offb, cnt, edges, meansum, invE,
                                             w2e, att2, bias2, h2, N);

    // classifier
    k_classify<<<(N * 8 + 255) / 256, 256, 0, stream>>>(h2, wc, bc, out, N);
}